// Round 4
// baseline (2784.247 us; speedup 1.0000x reference)
//
#include <hip/hip_runtime.h>

#define NEG_SLOPE 0.2f
#define NPB 128            // nodes per bucket (dst >> 7); requires N <= 131072
#define MAXB 1024          // max buckets

// ===========================================================================
// P0: bucket edge counts via block-local LDS histogram (fire-and-forget
// global atomics, one per (block,bucket))
// ===========================================================================
__global__ void p0_count(const int* __restrict__ dst, int* __restrict__ bcnt,
                         int E, int nbuck)
{
    __shared__ int hist[MAXB];
    for (int b = threadIdx.x; b < nbuck; b += blockDim.x) hist[b] = 0;
    __syncthreads();
    int tile = blockIdx.x * 4096;
    int cnt = min(4096, E - tile);
    for (int k = threadIdx.x; k < cnt; k += blockDim.x)
        atomicAdd(&hist[dst[tile + k] >> 7], 1);
    __syncthreads();
    for (int b = threadIdx.x; b < nbuck; b += blockDim.x) {
        int v = hist[b];
        if (v) atomicAdd(&bcnt[b], v);
    }
}

// ===========================================================================
// P1: exclusive scan of bucket counts (single block, 1024 threads)
// ===========================================================================
__global__ void p1_scan(const int* __restrict__ bcnt, int* __restrict__ bbase,
                        int* __restrict__ bcur, int nbuck)
{
    __shared__ int sm[MAXB];
    int t = threadIdx.x;
    int v = (t < nbuck) ? bcnt[t] : 0;
    sm[t] = v;
    __syncthreads();
    for (int off = 1; off < MAXB; off <<= 1) {
        int x = (t >= off) ? sm[t - off] : 0;
        __syncthreads();
        sm[t] += x;
        __syncthreads();
    }
    if (t < nbuck) { int e = sm[t] - v; bbase[t] = e; bcur[t] = e; }
}

// ===========================================================================
// P2: scatter edges into bucket regions. Per 4096-edge tile: LDS histogram,
// one returning global atomic per (block,bucket) to reserve space, LDS-atomic
// ranking, packed write (src<<7)|(dst&127).
// ===========================================================================
__global__ void p2_scatter(const int* __restrict__ src, const int* __restrict__ dst,
                           int* __restrict__ bcur, int* __restrict__ ebuf,
                           int E, int nbuck)
{
    __shared__ int hist[MAXB];
    __shared__ int base[MAXB];
    __shared__ int pk[4096];
    __shared__ unsigned short pb[4096];
    for (int b = threadIdx.x; b < nbuck; b += blockDim.x) hist[b] = 0;
    __syncthreads();
    int tile = blockIdx.x * 4096;
    int cnt = min(4096, E - tile);
    for (int k = threadIdx.x; k < cnt; k += blockDim.x) {
        int i = tile + k;
        int d = dst[i];
        int b = d >> 7;
        pk[k] = (src[i] << 7) | (d & 127);
        pb[k] = (unsigned short)b;
        atomicAdd(&hist[b], 1);
    }
    __syncthreads();
    for (int b = threadIdx.x; b < nbuck; b += blockDim.x) {
        int v = hist[b];
        base[b] = v ? atomicAdd(&bcur[b], v) : 0;
        hist[b] = 0;                      // reuse as rank cursor
    }
    __syncthreads();
    for (int k = threadIdx.x; k < cnt; k += blockDim.x) {
        int b = pb[k];
        int r = atomicAdd(&hist[b], 1);
        ebuf[base[b] + r] = pk[k];
    }
}

// ===========================================================================
// Fold attention vectors through layer weights (240 outputs), once per call.
// ===========================================================================
__global__ void k_fold(const float* __restrict__ W1,
                       const float* __restrict__ s1, const float* __restrict__ d1,
                       const float* __restrict__ W2,
                       const float* __restrict__ s2, const float* __restrict__ d2,
                       float* __restrict__ fold)
{
    int t = threadIdx.x;
    if (t < 24) {
        int h = t / 6, k = t % 6;
        float v = 0.f;
        for (int c = 0; c < 6; ++c) v += W1[k * 24 + h * 6 + c] * s1[h * 6 + c];
        fold[t] = v;
    } else if (t < 48) {
        int u = t - 24, h = u / 6, k = u % 6;
        float v = 0.f;
        for (int c = 0; c < 6; ++c) v += W1[k * 24 + h * 6 + c] * d1[h * 6 + c];
        fold[t] = v;
    } else if (t < 144) {
        int u = t - 48, h = u / 24, k = u % 24;
        float v = 0.f;
        for (int c = 0; c < 30; ++c) v += W2[k * 120 + h * 30 + c] * s2[h * 30 + c];
        fold[t] = v;
    } else if (t < 240) {
        int u = t - 144, h = u / 24, k = u % 24;
        float v = 0.f;
        for (int c = 0; c < 30; ++c) v += W2[k * 120 + h * 30 + c] * d2[h * 30 + c];
        fold[t] = v;
    }
}

// ===========================================================================
// K1: layer-1 logits directly from x
// ===========================================================================
__global__ void k1_logits(const float* __restrict__ x,
                          const float* __restrict__ fold,
                          float* __restrict__ as1, float* __restrict__ ad1, int N)
{
    int n = blockIdx.x * blockDim.x + threadIdx.x;
    if (n >= N) return;
    float xv[6];
#pragma unroll
    for (int k = 0; k < 6; ++k) xv[k] = x[n * 6 + k];
#pragma unroll
    for (int h = 0; h < 4; ++h) {
        float as = 0.f, ad = 0.f;
#pragma unroll
        for (int k = 0; k < 6; ++k) {
            as += xv[k] * fold[h * 6 + k];
            ad += xv[k] * fold[24 + h * 6 + k];
        }
        as1[n * 4 + h] = as;
        ad1[n * 4 + h] = ad;
    }
}

// ===========================================================================
// P4: layer-1 gather, one block per bucket. Accumulate in x-space (6-dim)
// per (node,head) in LDS via ds_add_f32; init with self-loop; finalize
// projects through W1_h -> g1 = relu(m @ W1_h + b1).
// LDS stride 29 (odd) spreads banks.
// ===========================================================================
__global__ void p4_gather1(const int* __restrict__ bbase, const int* __restrict__ bcnt,
                           const int* __restrict__ ebuf,
                           const float* __restrict__ x,
                           const float* __restrict__ as1, const float* __restrict__ ad1,
                           const float* __restrict__ W1, const float* __restrict__ b1,
                           float* __restrict__ g1, int N)
{
    __shared__ float lds[NPB * 29];     // [ln]: h*7+c (c<6 acc, c==6 den)
    __shared__ float adl[NPB * 5];      // [ln*5+h]
    int b = blockIdx.x;
    int n0 = b * NPB;

    for (int p = threadIdx.x; p < NPB * 4; p += blockDim.x) {
        int ln = p >> 2, h = p & 3;
        int n = n0 + ln;
        if (n < N) {
            float adv = ad1[n * 4 + h];
            adl[ln * 5 + h] = adv;
            float e0 = as1[n * 4 + h] + adv;
            e0 = e0 > 0.f ? e0 : NEG_SLOPE * e0;
            float w = expf(e0);
            const float* xp = x + (size_t)n * 6;
            float* a = &lds[ln * 29 + h * 7];
#pragma unroll
            for (int c = 0; c < 6; ++c) a[c] = w * xp[c];
            a[6] = w;
        }
    }
    __syncthreads();

    int es = bbase[b], ec = bcnt[b];
    for (int k = threadIdx.x; k < ec; k += blockDim.x) {
        int v = ebuf[es + k];
        int s = v >> 7, ln = v & 127;
        float4 a4 = *(const float4*)(as1 + (size_t)s * 4);
        const float2* xp = (const float2*)(x + (size_t)s * 6);
        float2 x01 = xp[0], x23 = xp[1], x45 = xp[2];
        float av[4] = {a4.x, a4.y, a4.z, a4.w};
#pragma unroll
        for (int h = 0; h < 4; ++h) {
            float e = av[h] + adl[ln * 5 + h];
            e = e > 0.f ? e : NEG_SLOPE * e;
            float w = expf(e);
            float* a = &lds[ln * 29 + h * 7];
            atomicAdd(&a[0], w * x01.x);
            atomicAdd(&a[1], w * x01.y);
            atomicAdd(&a[2], w * x23.x);
            atomicAdd(&a[3], w * x23.y);
            atomicAdd(&a[4], w * x45.x);
            atomicAdd(&a[5], w * x45.y);
            atomicAdd(&a[6], w);
        }
    }
    __syncthreads();

    for (int p = threadIdx.x; p < NPB * 4; p += blockDim.x) {
        int ln = p >> 2, h = p & 3;
        int n = n0 + ln;
        if (n >= N) continue;
        const float* a = &lds[ln * 29 + h * 7];
        float inv = 1.f / (a[6] + 1e-16f);
        float m[6];
#pragma unroll
        for (int k = 0; k < 6; ++k) m[k] = a[k] * inv;
#pragma unroll
        for (int c = 0; c < 6; ++c) {
            float vv = b1[h * 6 + c];
#pragma unroll
            for (int k = 0; k < 6; ++k) vv += m[k] * W1[k * 24 + h * 6 + c];
            g1[(size_t)n * 24 + h * 6 + c] = vv > 0.f ? vv : 0.f;
        }
    }
}

// ===========================================================================
// K3: layer-2 logits from g1 with folded vectors
// ===========================================================================
__global__ void k3_logits(const float* __restrict__ g1,
                          const float* __restrict__ fold,
                          float* __restrict__ as2, float* __restrict__ ad2, int N)
{
    int n = blockIdx.x * blockDim.x + threadIdx.x;
    if (n >= N) return;
    float g[24];
    const float4* gp = (const float4*)(g1 + (size_t)n * 24);
#pragma unroll
    for (int q = 0; q < 6; ++q) {
        float4 v = gp[q];
        g[q * 4 + 0] = v.x; g[q * 4 + 1] = v.y; g[q * 4 + 2] = v.z; g[q * 4 + 3] = v.w;
    }
#pragma unroll
    for (int h = 0; h < 4; ++h) {
        float as = 0.f, ad = 0.f;
#pragma unroll
        for (int k = 0; k < 24; ++k) {
            as += g[k] * fold[48 + h * 24 + k];
            ad += g[k] * fold[144 + h * 24 + k];
        }
        as2[n * 4 + h] = as;
        ad2[n * 4 + h] = ad;
    }
}

// ===========================================================================
// P6: layer-2 gather (24-dim g1-space) in LDS + fused head-mean + MLP.
// One block per bucket; per-(node,head) 24 acc + 1 den in LDS (stride 101).
// Finalize: quad (ln,h) workers project W2_h (24->30), shfl-xor head sum,
// lane h==0 does mean + b2 + relu + MLP 30->15->2 -> out.
// ===========================================================================
__global__ void p6_gather2(const int* __restrict__ bbase, const int* __restrict__ bcnt,
                           const int* __restrict__ ebuf,
                           const float* __restrict__ g1,
                           const float* __restrict__ as2, const float* __restrict__ ad2,
                           const float* __restrict__ W2, const float* __restrict__ b2,
                           const float* __restrict__ fw1, const float* __restrict__ fb1,
                           const float* __restrict__ fw2, const float* __restrict__ fb2,
                           float* __restrict__ out, int N)
{
    __shared__ float lds[NPB * 101];    // [ln]: h*25+k (k<24 acc, k==24 den)
    __shared__ float adl[NPB * 5];
    int b = blockIdx.x;
    int n0 = b * NPB;

    for (int p = threadIdx.x; p < NPB * 4; p += blockDim.x) {
        int ln = p >> 2, h = p & 3;
        int n = n0 + ln;
        if (n < N) {
            float adv = ad2[n * 4 + h];
            adl[ln * 5 + h] = adv;
            float e0 = as2[n * 4 + h] + adv;
            e0 = e0 > 0.f ? e0 : NEG_SLOPE * e0;
            float w = expf(e0);
            const float* gp = g1 + (size_t)n * 24;
            float* a = &lds[ln * 101 + h * 25];
#pragma unroll
            for (int k = 0; k < 24; ++k) a[k] = w * gp[k];
            a[24] = w;
        }
    }
    __syncthreads();

    int es = bbase[b], ec = bcnt[b];
    for (int k = threadIdx.x; k < ec; k += blockDim.x) {
        int v = ebuf[es + k];
        int s = v >> 7, ln = v & 127;
        float4 a4 = *(const float4*)(as2 + (size_t)s * 4);
        const float4* gp = (const float4*)(g1 + (size_t)s * 24);
        float gv[24];
#pragma unroll
        for (int q = 0; q < 6; ++q) {
            float4 t = gp[q];
            gv[q * 4 + 0] = t.x; gv[q * 4 + 1] = t.y;
            gv[q * 4 + 2] = t.z; gv[q * 4 + 3] = t.w;
        }
        float av[4] = {a4.x, a4.y, a4.z, a4.w};
#pragma unroll
        for (int h = 0; h < 4; ++h) {
            float e = av[h] + adl[ln * 5 + h];
            e = e > 0.f ? e : NEG_SLOPE * e;
            float w = expf(e);
            float* a = &lds[ln * 101 + h * 25];
#pragma unroll
            for (int c = 0; c < 24; ++c) atomicAdd(&a[c], w * gv[c]);
            atomicAdd(&a[24], w);
        }
    }
    __syncthreads();

    for (int p = threadIdx.x; p < NPB * 4; p += blockDim.x) {
        int ln = p >> 2, h = p & 3;
        int n = n0 + ln;
        if (n >= N) continue;            // whole quad skips together
        const float* a = &lds[ln * 101 + h * 25];
        float inv = 1.f / (a[24] + 1e-16f);
        float m[24];
#pragma unroll
        for (int k = 0; k < 24; ++k) m[k] = a[k] * inv;

        float zz[30];
#pragma unroll
        for (int c = 0; c < 30; ++c) {
            float v = 0.f;
#pragma unroll
            for (int k = 0; k < 24; ++k) v += m[k] * W2[k * 120 + h * 30 + c];
            v += __shfl_xor(v, 1);
            v += __shfl_xor(v, 2);
            zz[c] = v;                   // head sum on all 4 quad lanes
        }
        if (h == 0) {
#pragma unroll
            for (int c = 0; c < 30; ++c) {
                float v = 0.25f * zz[c] + b2[c];
                zz[c] = v > 0.f ? v : 0.f;
            }
            float m2[15];
#pragma unroll
            for (int j = 0; j < 15; ++j) {
                float v = fb1[j];
#pragma unroll
                for (int c = 0; c < 30; ++c) v += zz[c] * fw1[c * 15 + j];
                m2[j] = v > 0.f ? v : 0.f;
            }
#pragma unroll
            for (int k = 0; k < 2; ++k) {
                float v = fb2[k];
#pragma unroll
                for (int j = 0; j < 15; ++j) v += m2[j] * fw2[j * 2 + k];
                out[(size_t)n * 2 + k] = v;
            }
        }
    }
}

// ===========================================================================
extern "C" void kernel_launch(void* const* d_in, const int* in_sizes, int n_in,
                              void* d_out, int out_size, void* d_ws, size_t ws_size,
                              hipStream_t stream)
{
    const float* x    = (const float*)d_in[0];
    const int*   ei   = (const int*)  d_in[1];
    // d_in[2] = edge_attr (ignored)
    const float* w1   = (const float*)d_in[3];
    const float* as1w = (const float*)d_in[4];
    const float* ad1w = (const float*)d_in[5];
    const float* b1   = (const float*)d_in[6];
    const float* w2   = (const float*)d_in[7];
    const float* as2w = (const float*)d_in[8];
    const float* ad2w = (const float*)d_in[9];
    const float* b2   = (const float*)d_in[10];
    const float* fw1  = (const float*)d_in[11];
    const float* fb1  = (const float*)d_in[12];
    const float* fw2  = (const float*)d_in[13];
    const float* fb2  = (const float*)d_in[14];

    const int N = in_sizes[0] / 6;
    const int E = in_sizes[1] / 2;
    const int* src = ei;
    const int* dst = ei + E;
    const int nbuck = (N + NPB - 1) / NPB;     // <= 1024 for N <= 131072

    float* ws = (float*)d_ws;
    size_t off = 0;
    float* as1  = ws + off; off += (size_t)N * 4;
    float* ad1  = ws + off; off += (size_t)N * 4;
    float* g1   = ws + off; off += (size_t)N * 24;
    float* as2  = ws + off; off += (size_t)N * 4;
    float* ad2  = ws + off; off += (size_t)N * 4;
    float* fold = ws + off; off += 256;

    int* iw = (int*)(ws + off);
    int* bcnt  = iw;                // zeroed each call
    int* bbase = iw + MAXB;
    int* bcur  = iw + 2 * MAXB;
    int* ebuf  = iw + 3 * MAXB;     // E packed edges

    hipMemsetAsync(bcnt, 0, MAXB * sizeof(int), stream);

    const int B = 256;
    const int NB  = (N + B - 1) / B;
    const int TB  = (E + 4095) / 4096;

    k_fold    <<<1, 256, 0, stream>>>(w1, as1w, ad1w, w2, as2w, ad2w, fold);

    // bucket build
    p0_count  <<<TB, B, 0, stream>>>(dst, bcnt, E, nbuck);
    p1_scan   <<<1, MAXB, 0, stream>>>(bcnt, bbase, bcur, nbuck);
    p2_scatter<<<TB, B, 0, stream>>>(src, dst, bcur, ebuf, E, nbuck);

    // layer 1
    k1_logits <<<NB, B, 0, stream>>>(x, fold, as1, ad1, N);
    p4_gather1<<<nbuck, B, 0, stream>>>(bbase, bcnt, ebuf, x, as1, ad1, w1, b1, g1, N);

    // layer 2 + fused MLP head
    k3_logits <<<NB, B, 0, stream>>>(g1, fold, as2, ad2, N);
    p6_gather2<<<nbuck, B, 0, stream>>>(bbase, bcnt, ebuf, g1, as2, ad2, w2, b2,
                                        fw1, fb1, fw2, fb2, (float*)d_out, N);
}

// Round 5
// 388.183 us; speedup vs baseline: 7.1725x; 7.1725x over previous
//
#include <hip/hip_runtime.h>

#define NEG_SLOPE 0.2f
#define NPB 128            // nodes per bucket (dst >> 7); requires N <= 131072
#define MAXB 1024          // max buckets

// ===========================================================================
// P0: bucket edge counts via block-local LDS histogram (one fire-and-forget
// global atomic per (block,bucket))
// ===========================================================================
__global__ void p0_count(const int* __restrict__ dst, int* __restrict__ bcnt,
                         int E, int nbuck)
{
    __shared__ int hist[MAXB];
    for (int b = threadIdx.x; b < nbuck; b += blockDim.x) hist[b] = 0;
    __syncthreads();
    int tile = blockIdx.x * 4096;
    int cnt = min(4096, E - tile);
    for (int k = threadIdx.x; k < cnt; k += blockDim.x)
        atomicAdd(&hist[dst[tile + k] >> 7], 1);
    __syncthreads();
    for (int b = threadIdx.x; b < nbuck; b += blockDim.x) {
        int v = hist[b];
        if (v) atomicAdd(&bcnt[b], v);
    }
}

// ===========================================================================
// P1: exclusive scan of bucket counts (single block, 1024 threads)
// ===========================================================================
__global__ void p1_scan(const int* __restrict__ bcnt, int* __restrict__ bbase,
                        int* __restrict__ bcur, int nbuck)
{
    __shared__ int sm[MAXB];
    int t = threadIdx.x;
    int v = (t < nbuck) ? bcnt[t] : 0;
    sm[t] = v;
    __syncthreads();
    for (int off = 1; off < MAXB; off <<= 1) {
        int x = (t >= off) ? sm[t - off] : 0;
        __syncthreads();
        sm[t] += x;
        __syncthreads();
    }
    if (t < nbuck) { int e = sm[t] - v; bbase[t] = e; bcur[t] = e; }
}

// ===========================================================================
// P2: scatter edges into bucket regions (unordered within bucket). Per
// 4096-edge tile: LDS histogram, one returning global atomic per
// (block,bucket), LDS ranking, packed write (src<<7)|(dst&127).
// ===========================================================================
__global__ void p2_scatter(const int* __restrict__ src, const int* __restrict__ dst,
                           int* __restrict__ bcur, int* __restrict__ ebuf,
                           int E, int nbuck)
{
    __shared__ int hist[MAXB];
    __shared__ int base[MAXB];
    __shared__ int pk[4096];
    __shared__ unsigned short pb[4096];
    for (int b = threadIdx.x; b < nbuck; b += blockDim.x) hist[b] = 0;
    __syncthreads();
    int tile = blockIdx.x * 4096;
    int cnt = min(4096, E - tile);
    for (int k = threadIdx.x; k < cnt; k += blockDim.x) {
        int i = tile + k;
        int d = dst[i];
        int b = d >> 7;
        pk[k] = (src[i] << 7) | (d & 127);
        pb[k] = (unsigned short)b;
        atomicAdd(&hist[b], 1);
    }
    __syncthreads();
    for (int b = threadIdx.x; b < nbuck; b += blockDim.x) {
        int v = hist[b];
        base[b] = v ? atomicAdd(&bcur[b], v) : 0;
        hist[b] = 0;                      // reuse as rank cursor
    }
    __syncthreads();
    for (int k = threadIdx.x; k < cnt; k += blockDim.x) {
        int b = pb[k];
        int r = atomicAdd(&hist[b], 1);
        ebuf[base[b] + r] = pk[k];
    }
}

// ===========================================================================
// P3: within-bucket counting sort -> exact per-node CSR. One block per
// bucket: LDS histogram over 128 local nodes, 128-wide scan, rank+scatter
// (unpacking to plain src). All contention on 128 LDS counters.
// ===========================================================================
__global__ void p3_sort(const int* __restrict__ bbase, const int* __restrict__ bcnt,
                        const int* __restrict__ ebuf,
                        int* __restrict__ rowp, int* __restrict__ deg,
                        int* __restrict__ esrc, int N)
{
    __shared__ int hist[NPB];
    __shared__ int ls[NPB];
    int b = blockIdx.x;
    int n0 = b * NPB;
    if (threadIdx.x < NPB) hist[threadIdx.x] = 0;
    __syncthreads();
    int es = bbase[b], ec = bcnt[b];
    for (int k = threadIdx.x; k < ec; k += blockDim.x)
        atomicAdd(&hist[ebuf[es + k] & 127], 1);
    __syncthreads();
    if (threadIdx.x < NPB) ls[threadIdx.x] = hist[threadIdx.x];
    __syncthreads();
    for (int off = 1; off < NPB; off <<= 1) {
        int v = 0;
        if (threadIdx.x < NPB && threadIdx.x >= off) v = ls[threadIdx.x - off];
        __syncthreads();
        if (threadIdx.x < NPB) ls[threadIdx.x] += v;
        __syncthreads();
    }
    if (threadIdx.x < NPB) {
        int ex = ls[threadIdx.x] - hist[threadIdx.x];   // exclusive
        ls[threadIdx.x] = ex;
        int n = n0 + threadIdx.x;
        if (n < N) { rowp[n] = es + ex; deg[n] = hist[threadIdx.x]; }
        hist[threadIdx.x] = 0;            // reuse as cursor
    }
    __syncthreads();
    for (int k = threadIdx.x; k < ec; k += blockDim.x) {
        int v = ebuf[es + k];
        int ln = v & 127;
        int r = atomicAdd(&hist[ln], 1);
        esrc[es + ls[ln] + r] = v >> 7;
    }
}

// ===========================================================================
// Fold attention vectors through layer weights (240 outputs):
//  fold[0..24)    asv1[h][k]   fold[24..48) adv1
//  fold[48..144)  asv2[h][k]   fold[144..240) adv2
// ===========================================================================
__global__ void k_fold(const float* __restrict__ W1,
                       const float* __restrict__ s1, const float* __restrict__ d1,
                       const float* __restrict__ W2,
                       const float* __restrict__ s2, const float* __restrict__ d2,
                       float* __restrict__ fold)
{
    int t = threadIdx.x;
    if (t < 24) {
        int h = t / 6, k = t % 6;
        float v = 0.f;
        for (int c = 0; c < 6; ++c) v += W1[k * 24 + h * 6 + c] * s1[h * 6 + c];
        fold[t] = v;
    } else if (t < 48) {
        int u = t - 24, h = u / 6, k = u % 6;
        float v = 0.f;
        for (int c = 0; c < 6; ++c) v += W1[k * 24 + h * 6 + c] * d1[h * 6 + c];
        fold[t] = v;
    } else if (t < 144) {
        int u = t - 48, h = u / 24, k = u % 24;
        float v = 0.f;
        for (int c = 0; c < 30; ++c) v += W2[k * 120 + h * 30 + c] * s2[h * 30 + c];
        fold[t] = v;
    } else if (t < 240) {
        int u = t - 144, h = u / 24, k = u % 24;
        float v = 0.f;
        for (int c = 0; c < 30; ++c) v += W2[k * 120 + h * 30 + c] * d2[h * 30 + c];
        fold[t] = v;
    }
}

// ===========================================================================
// K1: layer-1 attention logits directly from x
// ===========================================================================
__global__ void k1_logits(const float* __restrict__ x,
                          const float* __restrict__ fold,
                          float* __restrict__ as1, float* __restrict__ ad1, int N)
{
    int n = blockIdx.x * blockDim.x + threadIdx.x;
    if (n >= N) return;
    float xv[6];
#pragma unroll
    for (int k = 0; k < 6; ++k) xv[k] = x[n * 6 + k];
#pragma unroll
    for (int h = 0; h < 4; ++h) {
        float as = 0.f, ad = 0.f;
#pragma unroll
        for (int k = 0; k < 6; ++k) {
            as += xv[k] * fold[h * 6 + k];
            ad += xv[k] * fold[24 + h * 6 + k];
        }
        as1[n * 4 + h] = as;
        ad1[n * 4 + h] = ad;
    }
}

// ===========================================================================
// Gather layer 1 in x-space (6-dim). One thread per (node, head); quads of
// lanes share the node so x[s]/as1[s] loads merge. Register accumulation.
// ===========================================================================
__global__ void k_gather1(const int* __restrict__ rowp, const int* __restrict__ deg,
                          const int* __restrict__ esrc,
                          const float* __restrict__ x,
                          const float* __restrict__ as1, const float* __restrict__ ad1,
                          const float* __restrict__ W1, const float* __restrict__ b1,
                          float* __restrict__ g1, int N)
{
    int t = blockIdx.x * blockDim.x + threadIdx.x;
    int n = t >> 2;
    if (n >= N) return;
    int h = t & 3;
    float adn = ad1[n * 4 + h];

    // self loop
    float e0 = as1[n * 4 + h] + adn;
    e0 = e0 > 0.f ? e0 : NEG_SLOPE * e0;
    float w = expf(e0);
    float den = w;
    float acc[6];
    {
        const float2* xp = (const float2*)(x + (size_t)n * 6);
        float2 a = xp[0], b = xp[1], c = xp[2];
        acc[0] = w * a.x; acc[1] = w * a.y; acc[2] = w * b.x;
        acc[3] = w * b.y; acc[4] = w * c.x; acc[5] = w * c.y;
    }
    int start = rowp[n], cnt = deg[n];
    for (int k = 0; k < cnt; ++k) {
        int s = esrc[start + k];
        float e = as1[s * 4 + h] + adn;
        e = e > 0.f ? e : NEG_SLOPE * e;
        w = expf(e);
        den += w;
        const float2* xp = (const float2*)(x + (size_t)s * 6);
        float2 a = xp[0], b = xp[1], c = xp[2];
        acc[0] += w * a.x; acc[1] += w * a.y; acc[2] += w * b.x;
        acc[3] += w * b.y; acc[4] += w * c.x; acc[5] += w * c.y;
    }
    float inv = 1.f / (den + 1e-16f);
    float m[6];
#pragma unroll
    for (int k = 0; k < 6; ++k) m[k] = acc[k] * inv;
#pragma unroll
    for (int c = 0; c < 6; ++c) {
        float v = b1[h * 6 + c];
#pragma unroll
        for (int k = 0; k < 6; ++k) v += m[k] * W1[k * 24 + h * 6 + c];
        g1[(size_t)n * 24 + h * 6 + c] = v > 0.f ? v : 0.f;
    }
}

// ===========================================================================
// K3: layer-2 logits from g1 with folded vectors
// ===========================================================================
__global__ void k3_logits(const float* __restrict__ g1,
                          const float* __restrict__ fold,
                          float* __restrict__ as2, float* __restrict__ ad2, int N)
{
    int n = blockIdx.x * blockDim.x + threadIdx.x;
    if (n >= N) return;
    float g[24];
    const float4* gp = (const float4*)(g1 + (size_t)n * 24);
#pragma unroll
    for (int q = 0; q < 6; ++q) {
        float4 v = gp[q];
        g[q * 4 + 0] = v.x; g[q * 4 + 1] = v.y; g[q * 4 + 2] = v.z; g[q * 4 + 3] = v.w;
    }
#pragma unroll
    for (int h = 0; h < 4; ++h) {
        float as = 0.f, ad = 0.f;
#pragma unroll
        for (int k = 0; k < 24; ++k) {
            as += g[k] * fold[48 + h * 24 + k];
            ad += g[k] * fold[144 + h * 24 + k];
        }
        as2[n * 4 + h] = as;
        ad2[n * 4 + h] = ad;
    }
}

// ===========================================================================
// Gather layer 2 in g1-space (24-dim), one thread per (node, head), register
// accumulation. Epilogue: project W2_h (24->30), quad shfl-xor head sum,
// lane h==0 does mean + b2 + relu + fused MLP 30->15->2.
// ===========================================================================
__global__ void k_gather2(const int* __restrict__ rowp, const int* __restrict__ deg,
                          const int* __restrict__ esrc,
                          const float* __restrict__ g1,
                          const float* __restrict__ as2, const float* __restrict__ ad2,
                          const float* __restrict__ W2, const float* __restrict__ b2,
                          const float* __restrict__ fw1, const float* __restrict__ fb1,
                          const float* __restrict__ fw2, const float* __restrict__ fb2,
                          float* __restrict__ out, int N)
{
    int t = blockIdx.x * blockDim.x + threadIdx.x;
    int n = t >> 2;
    if (n >= N) return;
    int h = t & 3;
    float adn = ad2[n * 4 + h];

    float acc[24];
    float e0 = as2[n * 4 + h] + adn;
    e0 = e0 > 0.f ? e0 : NEG_SLOPE * e0;
    float w = expf(e0);
    float den = w;
    {
        const float4* gp = (const float4*)(g1 + (size_t)n * 24);
#pragma unroll
        for (int q = 0; q < 6; ++q) {
            float4 v = gp[q];
            acc[q * 4 + 0] = w * v.x; acc[q * 4 + 1] = w * v.y;
            acc[q * 4 + 2] = w * v.z; acc[q * 4 + 3] = w * v.w;
        }
    }
    int start = rowp[n], cnt = deg[n];
    for (int k = 0; k < cnt; ++k) {
        int s = esrc[start + k];
        float e = as2[s * 4 + h] + adn;
        e = e > 0.f ? e : NEG_SLOPE * e;
        w = expf(e);
        den += w;
        const float4* gp = (const float4*)(g1 + (size_t)s * 24);
#pragma unroll
        for (int q = 0; q < 6; ++q) {
            float4 v = gp[q];
            acc[q * 4 + 0] += w * v.x; acc[q * 4 + 1] += w * v.y;
            acc[q * 4 + 2] += w * v.z; acc[q * 4 + 3] += w * v.w;
        }
    }
    float inv = 1.f / (den + 1e-16f);
#pragma unroll
    for (int k = 0; k < 24; ++k) acc[k] *= inv;

    float zz[30];
#pragma unroll
    for (int c = 0; c < 30; ++c) {
        float v = 0.f;
#pragma unroll
        for (int k = 0; k < 24; ++k) v += acc[k] * W2[k * 120 + h * 30 + c];
        v += __shfl_xor(v, 1);
        v += __shfl_xor(v, 2);
        zz[c] = v;          // full head-sum on all 4 quad lanes
    }
    if (h == 0) {
#pragma unroll
        for (int c = 0; c < 30; ++c) {
            float v = 0.25f * zz[c] + b2[c];
            zz[c] = v > 0.f ? v : 0.f;
        }
        float m2[15];
#pragma unroll
        for (int j = 0; j < 15; ++j) {
            float v = fb1[j];
#pragma unroll
            for (int c = 0; c < 30; ++c) v += zz[c] * fw1[c * 15 + j];
            m2[j] = v > 0.f ? v : 0.f;
        }
#pragma unroll
        for (int k = 0; k < 2; ++k) {
            float v = fb2[k];
#pragma unroll
            for (int j = 0; j < 15; ++j) v += m2[j] * fw2[j * 2 + k];
            out[(size_t)n * 2 + k] = v;
        }
    }
}

// ===========================================================================
extern "C" void kernel_launch(void* const* d_in, const int* in_sizes, int n_in,
                              void* d_out, int out_size, void* d_ws, size_t ws_size,
                              hipStream_t stream)
{
    const float* x    = (const float*)d_in[0];
    const int*   ei   = (const int*)  d_in[1];
    // d_in[2] = edge_attr (ignored)
    const float* w1   = (const float*)d_in[3];
    const float* as1w = (const float*)d_in[4];
    const float* ad1w = (const float*)d_in[5];
    const float* b1   = (const float*)d_in[6];
    const float* w2   = (const float*)d_in[7];
    const float* as2w = (const float*)d_in[8];
    const float* ad2w = (const float*)d_in[9];
    const float* b2   = (const float*)d_in[10];
    const float* fw1  = (const float*)d_in[11];
    const float* fb1  = (const float*)d_in[12];
    const float* fw2  = (const float*)d_in[13];
    const float* fb2  = (const float*)d_in[14];

    const int N = in_sizes[0] / 6;
    const int E = in_sizes[1] / 2;
    const int* src = ei;
    const int* dst = ei + E;
    const int nbuck = (N + NPB - 1) / NPB;     // <= 1024 for N <= 131072

    float* ws = (float*)d_ws;
    size_t off = 0;
    float* as1  = ws + off; off += (size_t)N * 4;
    float* ad1  = ws + off; off += (size_t)N * 4;
    float* g1   = ws + off; off += (size_t)N * 24;
    float* as2  = ws + off; off += (size_t)N * 4;
    float* ad2  = ws + off; off += (size_t)N * 4;
    float* fold = ws + off; off += 256;

    int* iw = (int*)(ws + off);
    size_t ioff = 0;
    int* bcnt  = iw + ioff; ioff += MAXB;      // zeroed each call
    int* bbase = iw + ioff; ioff += MAXB;
    int* bcur  = iw + ioff; ioff += MAXB;
    int* rowp  = iw + ioff; ioff += N;
    int* deg   = iw + ioff; ioff += N;
    int* ebuf  = iw + ioff; ioff += E;         // packed, bucket-grouped
    int* esrc  = iw + ioff; ioff += E;         // per-node CSR order
    // total ~42 MB of d_ws

    hipMemsetAsync(bcnt, 0, MAXB * sizeof(int), stream);

    const int B = 256;
    const int NB = (N + B - 1) / B;
    const int TB = (E + 4095) / 4096;
    const int QB = (N * 4 + B - 1) / B;

    k_fold    <<<1, 256, 0, stream>>>(w1, as1w, ad1w, w2, as2w, ad2w, fold);

    // CSR build: bucket + within-bucket counting sort
    p0_count  <<<TB, B, 0, stream>>>(dst, bcnt, E, nbuck);
    p1_scan   <<<1, MAXB, 0, stream>>>(bcnt, bbase, bcur, nbuck);
    p2_scatter<<<TB, B, 0, stream>>>(src, dst, bcur, ebuf, E, nbuck);
    p3_sort   <<<nbuck, B, 0, stream>>>(bbase, bcnt, ebuf, rowp, deg, esrc, N);

    // layer 1 (aggregate in 6-dim x-space, project through W1 after)
    k1_logits <<<NB, B, 0, stream>>>(x, fold, as1, ad1, N);
    k_gather1 <<<QB, B, 0, stream>>>(rowp, deg, esrc, x, as1, ad1, w1, b1, g1, N);

    // layer 2 (aggregate in 24-dim g1-space, project + fused MLP head)
    k3_logits <<<NB, B, 0, stream>>>(g1, fold, as2, ad2, N);
    k_gather2 <<<QB, B, 0, stream>>>(rowp, deg, esrc, g1, as2, ad2, w2, b2,
                                     fw1, fb1, fw2, fb2, (float*)d_out, N);
}

// Round 6
// 377.582 us; speedup vs baseline: 7.3739x; 1.0281x over previous
//
#include <hip/hip_runtime.h>
#include <hip/hip_fp16.h>

#define NEG_SLOPE 0.2f
#define NPB 128            // nodes per bucket (dst >> 7); requires N <= 131072
#define MAXB 1024          // max buckets

// ===========================================================================
// P0: bucket edge counts via block-local LDS histogram
// ===========================================================================
__global__ void p0_count(const int* __restrict__ dst, int* __restrict__ bcnt,
                         int E, int nbuck)
{
    __shared__ int hist[MAXB];
    for (int b = threadIdx.x; b < nbuck; b += blockDim.x) hist[b] = 0;
    __syncthreads();
    int tile = blockIdx.x * 4096;
    int cnt = min(4096, E - tile);
    for (int k = threadIdx.x; k < cnt; k += blockDim.x)
        atomicAdd(&hist[dst[tile + k] >> 7], 1);
    __syncthreads();
    for (int b = threadIdx.x; b < nbuck; b += blockDim.x) {
        int v = hist[b];
        if (v) atomicAdd(&bcnt[b], v);
    }
}

// ===========================================================================
// P1: exclusive scan of bucket counts (single block)
// ===========================================================================
__global__ void p1_scan(const int* __restrict__ bcnt, int* __restrict__ bbase,
                        int* __restrict__ bcur, int nbuck)
{
    __shared__ int sm[MAXB];
    int t = threadIdx.x;
    int v = (t < nbuck) ? bcnt[t] : 0;
    sm[t] = v;
    __syncthreads();
    for (int off = 1; off < MAXB; off <<= 1) {
        int x = (t >= off) ? sm[t - off] : 0;
        __syncthreads();
        sm[t] += x;
        __syncthreads();
    }
    if (t < nbuck) { int e = sm[t] - v; bbase[t] = e; bcur[t] = e; }
}

// ===========================================================================
// P2: scatter edges into bucket regions, packed (src<<7)|(dst&127)
// ===========================================================================
__global__ void p2_scatter(const int* __restrict__ src, const int* __restrict__ dst,
                           int* __restrict__ bcur, int* __restrict__ ebuf,
                           int E, int nbuck)
{
    __shared__ int hist[MAXB];
    __shared__ int base[MAXB];
    __shared__ int pk[4096];
    __shared__ unsigned short pb[4096];
    for (int b = threadIdx.x; b < nbuck; b += blockDim.x) hist[b] = 0;
    __syncthreads();
    int tile = blockIdx.x * 4096;
    int cnt = min(4096, E - tile);
    for (int k = threadIdx.x; k < cnt; k += blockDim.x) {
        int i = tile + k;
        int d = dst[i];
        int b = d >> 7;
        pk[k] = (src[i] << 7) | (d & 127);
        pb[k] = (unsigned short)b;
        atomicAdd(&hist[b], 1);
    }
    __syncthreads();
    for (int b = threadIdx.x; b < nbuck; b += blockDim.x) {
        int v = hist[b];
        base[b] = v ? atomicAdd(&bcur[b], v) : 0;
        hist[b] = 0;                      // reuse as rank cursor
    }
    __syncthreads();
    for (int k = threadIdx.x; k < cnt; k += blockDim.x) {
        int b = pb[k];
        int r = atomicAdd(&hist[b], 1);
        ebuf[base[b] + r] = pk[k];
    }
}

// ===========================================================================
// P3: within-bucket counting sort -> exact per-node CSR
// ===========================================================================
__global__ void p3_sort(const int* __restrict__ bbase, const int* __restrict__ bcnt,
                        const int* __restrict__ ebuf,
                        int* __restrict__ rowp, int* __restrict__ deg,
                        int* __restrict__ esrc, int N)
{
    __shared__ int hist[NPB];
    __shared__ int ls[NPB];
    int b = blockIdx.x;
    int n0 = b * NPB;
    if (threadIdx.x < NPB) hist[threadIdx.x] = 0;
    __syncthreads();
    int es = bbase[b], ec = bcnt[b];
    for (int k = threadIdx.x; k < ec; k += blockDim.x)
        atomicAdd(&hist[ebuf[es + k] & 127], 1);
    __syncthreads();
    if (threadIdx.x < NPB) ls[threadIdx.x] = hist[threadIdx.x];
    __syncthreads();
    for (int off = 1; off < NPB; off <<= 1) {
        int v = 0;
        if (threadIdx.x < NPB && threadIdx.x >= off) v = ls[threadIdx.x - off];
        __syncthreads();
        if (threadIdx.x < NPB) ls[threadIdx.x] += v;
        __syncthreads();
    }
    if (threadIdx.x < NPB) {
        int ex = ls[threadIdx.x] - hist[threadIdx.x];   // exclusive
        ls[threadIdx.x] = ex;
        int n = n0 + threadIdx.x;
        if (n < N) { rowp[n] = es + ex; deg[n] = hist[threadIdx.x]; }
        hist[threadIdx.x] = 0;            // reuse as cursor
    }
    __syncthreads();
    for (int k = threadIdx.x; k < ec; k += blockDim.x) {
        int v = ebuf[es + k];
        int ln = v & 127;
        int r = atomicAdd(&hist[ln], 1);
        esrc[es + ls[ln] + r] = v >> 7;
    }
}

// ===========================================================================
// Fold attention vectors through layer weights (240 outputs)
// ===========================================================================
__global__ void k_fold(const float* __restrict__ W1,
                       const float* __restrict__ s1, const float* __restrict__ d1,
                       const float* __restrict__ W2,
                       const float* __restrict__ s2, const float* __restrict__ d2,
                       float* __restrict__ fold)
{
    int t = threadIdx.x;
    if (t < 24) {
        int h = t / 6, k = t % 6;
        float v = 0.f;
        for (int c = 0; c < 6; ++c) v += W1[k * 24 + h * 6 + c] * s1[h * 6 + c];
        fold[t] = v;
    } else if (t < 48) {
        int u = t - 24, h = u / 6, k = u % 6;
        float v = 0.f;
        for (int c = 0; c < 6; ++c) v += W1[k * 24 + h * 6 + c] * d1[h * 6 + c];
        fold[t] = v;
    } else if (t < 144) {
        int u = t - 48, h = u / 24, k = u % 24;
        float v = 0.f;
        for (int c = 0; c < 30; ++c) v += W2[k * 120 + h * 30 + c] * s2[h * 30 + c];
        fold[t] = v;
    } else if (t < 240) {
        int u = t - 144, h = u / 24, k = u % 24;
        float v = 0.f;
        for (int c = 0; c < 30; ++c) v += W2[k * 120 + h * 30 + c] * d2[h * 30 + c];
        fold[t] = v;
    }
}

// ===========================================================================
// K1: layer-1 attention logits directly from x
// ===========================================================================
__global__ void k1_logits(const float* __restrict__ x,
                          const float* __restrict__ fold,
                          float* __restrict__ as1, float* __restrict__ ad1, int N)
{
    int n = blockIdx.x * blockDim.x + threadIdx.x;
    if (n >= N) return;
    float xv[6];
#pragma unroll
    for (int k = 0; k < 6; ++k) xv[k] = x[n * 6 + k];
#pragma unroll
    for (int h = 0; h < 4; ++h) {
        float as = 0.f, ad = 0.f;
#pragma unroll
        for (int k = 0; k < 6; ++k) {
            as += xv[k] * fold[h * 6 + k];
            ad += xv[k] * fold[24 + h * 6 + k];
        }
        as1[n * 4 + h] = as;
        ad1[n * 4 + h] = ad;
    }
}

// ===========================================================================
// Gather layer 1, 8 threads/node: o=t&7, head=o&3, half=o>>2. Each half
// walks alternate edges (chain ~deg/2); halves merged via shfl_xor(4).
// Epilogue (half0): project W1_h -> gc, write g1h (fp16), and fused layer-2
// logits as2/ad2 = gc . foldedW2 via 2 quad-shuffle rounds.
// ===========================================================================
__global__ void k_gather1(const int* __restrict__ rowp, const int* __restrict__ deg,
                          const int* __restrict__ esrc,
                          const float* __restrict__ x,
                          const float* __restrict__ as1, const float* __restrict__ ad1,
                          const float* __restrict__ W1, const float* __restrict__ b1,
                          const float* __restrict__ fold,
                          __half* __restrict__ g1h,
                          float* __restrict__ as2, float* __restrict__ ad2, int N)
{
    int t = blockIdx.x * blockDim.x + threadIdx.x;
    int n = t >> 3;
    if (n >= N) return;
    int o = t & 7;
    int h = o & 3;
    int half = o >> 2;
    float adn = ad1[n * 4 + h];

    float acc[6] = {0.f, 0.f, 0.f, 0.f, 0.f, 0.f};
    float den = 0.f;
    if (half == 0) {   // self loop
        float e0 = as1[n * 4 + h] + adn;
        e0 = e0 > 0.f ? e0 : NEG_SLOPE * e0;
        float w = expf(e0);
        den = w;
        const float2* xp = (const float2*)(x + (size_t)n * 6);
        float2 a = xp[0], b = xp[1], c = xp[2];
        acc[0] = w * a.x; acc[1] = w * a.y; acc[2] = w * b.x;
        acc[3] = w * b.y; acc[4] = w * c.x; acc[5] = w * c.y;
    }
    int start = rowp[n], cnt = deg[n];
    for (int k = half; k < cnt; k += 2) {
        int s = esrc[start + k];
        float e = as1[s * 4 + h] + adn;
        e = e > 0.f ? e : NEG_SLOPE * e;
        float w = expf(e);
        den += w;
        const float2* xp = (const float2*)(x + (size_t)s * 6);
        float2 a = xp[0], b = xp[1], c = xp[2];
        acc[0] += w * a.x; acc[1] += w * a.y; acc[2] += w * b.x;
        acc[3] += w * b.y; acc[4] += w * c.x; acc[5] += w * c.y;
    }
    // merge halves
    den += __shfl_xor(den, 4);
#pragma unroll
    for (int k = 0; k < 6; ++k) acc[k] += __shfl_xor(acc[k], 4);

    float inv = 1.f / (den + 1e-16f);
    float m[6];
#pragma unroll
    for (int k = 0; k < 6; ++k) m[k] = acc[k] * inv;

    // project W1_h: gc[c] = relu(m . W1[:, h*6+c] + b1)
    float gc[6];
#pragma unroll
    for (int c = 0; c < 6; ++c) {
        float v = b1[h * 6 + c];
#pragma unroll
        for (int k = 0; k < 6; ++k) v += m[k] * W1[k * 24 + h * 6 + c];
        gc[c] = v > 0.f ? v : 0.f;
    }
    // fused layer-2 logits: partial over this lane's 6 channels, for all 4
    // target heads; quad shfl-xor sums across the 4 channel-blocks.
    float pas[4], pad[4];
#pragma unroll
    for (int hh = 0; hh < 4; ++hh) {
        float a = 0.f, d = 0.f;
#pragma unroll
        for (int c = 0; c < 6; ++c) {
            a += gc[c] * fold[48 + hh * 24 + h * 6 + c];
            d += gc[c] * fold[144 + hh * 24 + h * 6 + c];
        }
        pas[hh] = a; pad[hh] = d;
    }
#pragma unroll
    for (int hh = 0; hh < 4; ++hh) {
        pas[hh] += __shfl_xor(pas[hh], 1);
        pas[hh] += __shfl_xor(pas[hh], 2);
        pad[hh] += __shfl_xor(pad[hh], 1);
        pad[hh] += __shfl_xor(pad[hh], 2);
    }
    if (half == 0) {
        // write fp16 g1 (3 dword stores, 4B-aligned)
        __half2 p0 = __floats2half2_rn(gc[0], gc[1]);
        __half2 p1 = __floats2half2_rn(gc[2], gc[3]);
        __half2 p2 = __floats2half2_rn(gc[4], gc[5]);
        unsigned int* gp = (unsigned int*)(g1h + (size_t)n * 24 + h * 6);
        gp[0] = *(unsigned int*)&p0;
        gp[1] = *(unsigned int*)&p1;
        gp[2] = *(unsigned int*)&p2;
        // lane h writes logits for head h (full sums identical on lanes 0-3)
        as2[n * 4 + h] = pas[h];
        ad2[n * 4 + h] = pad[h];
    }
}

// ===========================================================================
// Gather layer 2, 8 threads/node, fp16 g1, register accumulation.
// Epilogue: each half projects 15 of the 30 channels via W2_h, quad
// shfl-xor head sum, lane o==0 collects ch15-29 via xor(4) and runs
// mean + b2 + relu + MLP 30->15->2.
// ===========================================================================
__global__ void k_gather2(const int* __restrict__ rowp, const int* __restrict__ deg,
                          const int* __restrict__ esrc,
                          const __half* __restrict__ g1h,
                          const float* __restrict__ as2, const float* __restrict__ ad2,
                          const float* __restrict__ W2, const float* __restrict__ b2,
                          const float* __restrict__ fw1, const float* __restrict__ fb1,
                          const float* __restrict__ fw2, const float* __restrict__ fb2,
                          float* __restrict__ out, int N)
{
    int t = blockIdx.x * blockDim.x + threadIdx.x;
    int n = t >> 3;
    if (n >= N) return;
    int o = t & 7;
    int h = o & 3;
    int half = o >> 2;
    float adn = ad2[n * 4 + h];

    float acc[24];
#pragma unroll
    for (int k = 0; k < 24; ++k) acc[k] = 0.f;
    float den = 0.f;

    if (half == 0) {   // self loop
        float e0 = as2[n * 4 + h] + adn;
        e0 = e0 > 0.f ? e0 : NEG_SLOPE * e0;
        float w = expf(e0);
        den = w;
        const uint4* gp = (const uint4*)(g1h + (size_t)n * 24);
#pragma unroll
        for (int q = 0; q < 3; ++q) {
            uint4 u = gp[q];
            float2 f0 = __half22float2(*(__half2*)&u.x);
            float2 f1 = __half22float2(*(__half2*)&u.y);
            float2 f2 = __half22float2(*(__half2*)&u.z);
            float2 f3 = __half22float2(*(__half2*)&u.w);
            acc[q * 8 + 0] = w * f0.x; acc[q * 8 + 1] = w * f0.y;
            acc[q * 8 + 2] = w * f1.x; acc[q * 8 + 3] = w * f1.y;
            acc[q * 8 + 4] = w * f2.x; acc[q * 8 + 5] = w * f2.y;
            acc[q * 8 + 6] = w * f3.x; acc[q * 8 + 7] = w * f3.y;
        }
    }
    int start = rowp[n], cnt = deg[n];
    for (int k = half; k < cnt; k += 2) {
        int s = esrc[start + k];
        float e = as2[s * 4 + h] + adn;
        e = e > 0.f ? e : NEG_SLOPE * e;
        float w = expf(e);
        den += w;
        const uint4* gp = (const uint4*)(g1h + (size_t)s * 24);
#pragma unroll
        for (int q = 0; q < 3; ++q) {
            uint4 u = gp[q];
            float2 f0 = __half22float2(*(__half2*)&u.x);
            float2 f1 = __half22float2(*(__half2*)&u.y);
            float2 f2 = __half22float2(*(__half2*)&u.z);
            float2 f3 = __half22float2(*(__half2*)&u.w);
            acc[q * 8 + 0] += w * f0.x; acc[q * 8 + 1] += w * f0.y;
            acc[q * 8 + 2] += w * f1.x; acc[q * 8 + 3] += w * f1.y;
            acc[q * 8 + 4] += w * f2.x; acc[q * 8 + 5] += w * f2.y;
            acc[q * 8 + 6] += w * f3.x; acc[q * 8 + 7] += w * f3.y;
        }
    }
    // merge halves
    den += __shfl_xor(den, 4);
#pragma unroll
    for (int k = 0; k < 24; ++k) acc[k] += __shfl_xor(acc[k], 4);

    float inv = 1.f / (den + 1e-16f);
#pragma unroll
    for (int k = 0; k < 24; ++k) acc[k] *= inv;

    // project 15 channels per half: c = half*15 + cc
    float zz[15];
#pragma unroll
    for (int cc = 0; cc < 15; ++cc) {
        int c = half * 15 + cc;
        float v = 0.f;
#pragma unroll
        for (int k = 0; k < 24; ++k) v += acc[k] * W2[k * 120 + h * 30 + c];
        v += __shfl_xor(v, 1);
        v += __shfl_xor(v, 2);
        zz[cc] = v;          // head-summed; half0: ch 0-14, half1: ch 15-29
    }
    float zhi[15];
#pragma unroll
    for (int cc = 0; cc < 15; ++cc) zhi[cc] = __shfl_xor(zz[cc], 4);

    if (o == 0) {
        float z[30];
#pragma unroll
        for (int cc = 0; cc < 15; ++cc) {
            float v0 = 0.25f * zz[cc] + b2[cc];
            float v1 = 0.25f * zhi[cc] + b2[15 + cc];
            z[cc]      = v0 > 0.f ? v0 : 0.f;
            z[15 + cc] = v1 > 0.f ? v1 : 0.f;
        }
        float m2[15];
#pragma unroll
        for (int j = 0; j < 15; ++j) {
            float v = fb1[j];
#pragma unroll
            for (int c = 0; c < 30; ++c) v += z[c] * fw1[c * 15 + j];
            m2[j] = v > 0.f ? v : 0.f;
        }
#pragma unroll
        for (int k = 0; k < 2; ++k) {
            float v = fb2[k];
#pragma unroll
            for (int j = 0; j < 15; ++j) v += m2[j] * fw2[j * 2 + k];
            out[(size_t)n * 2 + k] = v;
        }
    }
}

// ===========================================================================
extern "C" void kernel_launch(void* const* d_in, const int* in_sizes, int n_in,
                              void* d_out, int out_size, void* d_ws, size_t ws_size,
                              hipStream_t stream)
{
    const float* x    = (const float*)d_in[0];
    const int*   ei   = (const int*)  d_in[1];
    // d_in[2] = edge_attr (ignored)
    const float* w1   = (const float*)d_in[3];
    const float* as1w = (const float*)d_in[4];
    const float* ad1w = (const float*)d_in[5];
    const float* b1   = (const float*)d_in[6];
    const float* w2   = (const float*)d_in[7];
    const float* as2w = (const float*)d_in[8];
    const float* ad2w = (const float*)d_in[9];
    const float* b2   = (const float*)d_in[10];
    const float* fw1  = (const float*)d_in[11];
    const float* fb1  = (const float*)d_in[12];
    const float* fw2  = (const float*)d_in[13];
    const float* fb2  = (const float*)d_in[14];

    const int N = in_sizes[0] / 6;
    const int E = in_sizes[1] / 2;
    const int* src = ei;
    const int* dst = ei + E;
    const int nbuck = (N + NPB - 1) / NPB;     // <= 1024 for N <= 131072

    float* ws = (float*)d_ws;
    size_t off = 0;
    float* as1  = ws + off; off += (size_t)N * 4;
    float* ad1  = ws + off; off += (size_t)N * 4;
    float* as2  = ws + off; off += (size_t)N * 4;
    float* ad2  = ws + off; off += (size_t)N * 4;
    float* fold = ws + off; off += 256;
    __half* g1h = (__half*)(ws + off); off += (size_t)N * 12;   // N*24 halfs

    int* iw = (int*)(ws + off);
    size_t ioff = 0;
    int* bcnt  = iw + ioff; ioff += MAXB;      // zeroed each call
    int* bbase = iw + ioff; ioff += MAXB;
    int* bcur  = iw + ioff; ioff += MAXB;
    int* rowp  = iw + ioff; ioff += N;
    int* deg   = iw + ioff; ioff += N;
    int* ebuf  = iw + ioff; ioff += E;         // packed, bucket-grouped
    int* esrc  = iw + ioff; ioff += E;         // per-node CSR order

    hipMemsetAsync(bcnt, 0, MAXB * sizeof(int), stream);

    const int B = 256;
    const int NB = (N + B - 1) / B;
    const int TB = (E + 4095) / 4096;
    const int OB = ((size_t)N * 8 + B - 1) / B;

    k_fold    <<<1, 256, 0, stream>>>(w1, as1w, ad1w, w2, as2w, ad2w, fold);

    // CSR build: bucket + within-bucket counting sort
    p0_count  <<<TB, B, 0, stream>>>(dst, bcnt, E, nbuck);
    p1_scan   <<<1, MAXB, 0, stream>>>(bcnt, bbase, bcur, nbuck);
    p2_scatter<<<TB, B, 0, stream>>>(src, dst, bcur, ebuf, E, nbuck);
    p3_sort   <<<nbuck, B, 0, stream>>>(bbase, bcnt, ebuf, rowp, deg, esrc, N);

    // layer 1 (x-space aggregation, W1 projection + fused layer-2 logits)
    k1_logits <<<NB, B, 0, stream>>>(x, fold, as1, ad1, N);
    k_gather1 <<<OB, B, 0, stream>>>(rowp, deg, esrc, x, as1, ad1, w1, b1,
                                     fold, g1h, as2, ad2, N);

    // layer 2 (fp16 g1 aggregation, W2 projection + fused MLP head)
    k_gather2 <<<OB, B, 0, stream>>>(rowp, deg, esrc, g1h, as2, ad2, w2, b2,
                                     fw1, fb1, fw2, fb2, (float*)d_out, N);
}